// Round 7
// baseline (196.540 us; speedup 1.0000x reference)
//
#include <hip/hip_runtime.h>
#include <math.h>

#define T_DIM 1000

typedef __attribute__((ext_vector_type(8))) short short8;
typedef __attribute__((ext_vector_type(16))) float f32x16;

static __device__ __forceinline__ short bf16_rn(float f) {
  union { float f; unsigned u; } v;
  v.f = f;
  unsigned r = v.u + 0x7fffu + ((v.u >> 16) & 1u);
  return (short)(r >> 16);
}

// weight conversion, both matrices in one launch (grid 768)
__global__ __launch_bounds__(256) void prep_w(const float* __restrict__ wq,
                                              const float* __restrict__ wp,
                                              short* __restrict__ wqb,
                                              short* __restrict__ wpb) {
  int i = blockIdx.x * 256 + threadIdx.x;
  if (i < 131072) wqb[i] = bf16_rn(wq[i]);
  int j = i - 131072;
  if (j >= 0 && j < 65536) wpb[j] = bf16_rn(wp[j]);
}

// ---------------- QKV: fused x-stage + MFMA GEMM M=512 K=256 Ntile=32 ------
// grid 1000 (b, t-tile of 4); 512 thr / 8 waves; wave wv: M=[wv*64,wv*64+64).
__global__ __launch_bounds__(512) void qkv_mfma(
    const float* __restrict__ x, const short* __restrict__ wb,
    const float* __restrict__ bias, const float* __restrict__ a_p,
    const float* __restrict__ gam, const float* __restrict__ bet,
    short* __restrict__ qkb, short* __restrict__ vpb) {
  __shared__ short Bs[32][264];
  __shared__ float lnS[8][32], lnQ[8][32];
  __shared__ float mu_s[32], ri_s[32];
  __shared__ float pb[512], pg[512], pe[512];
  int tid = threadIdx.x;
  int blk = blockIdx.x;
  int b = blk / 250;
  int t0 = (blk % 250) * 4;
  pb[tid] = bias[tid];
  pg[tid] = gam[tid];
  pe[tid] = bet[tid];
  {
    const float* xb = x + (size_t)b * 256 * 8000 + t0;
    float4 va[2][2];
#pragma unroll
    for (int i = 0; i < 2; ++i) {
      int u = tid + i * 512;
      int f = u & 7, cp = u >> 3;  // cp 0..127 -> c0 = 2*cp
      const float* pa = xb + ((size_t)(cp * 2) * 8 + f) * 1000;
      va[i][0] = *(const float4*)pa;          // c0,   t0..t0+3
      va[i][1] = *(const float4*)(pa + 8000); // c0+1, t0..t0+3
    }
#pragma unroll
    for (int i = 0; i < 2; ++i) {
      int u = tid + i * 512;
      int f = u & 7, cp = u >> 3;
      const float* fa = (const float*)&va[i][0];
      const float* fb = (const float*)&va[i][1];
#pragma unroll
      for (int tt = 0; tt < 4; ++tt) {
        unsigned lo = (unsigned short)bf16_rn(fa[tt]);
        unsigned hi = (unsigned short)bf16_rn(fb[tt]);
        *(unsigned*)&Bs[tt * 8 + f][cp * 2] = lo | (hi << 16);
      }
    }
  }
  __syncthreads();
  int lane = tid & 63, wv = tid >> 6;  // wv 0..7
  int h = lane >> 5, l31 = lane & 31;
  int m0 = wv * 64;
  f32x16 acc[2];
#pragma unroll
  for (int mt = 0; mt < 2; ++mt)
#pragma unroll
    for (int r = 0; r < 16; ++r) acc[mt][r] = 0.f;
  const short* wbase = wb + ((size_t)(m0 + l31)) * 256 + h * 8;
#pragma unroll
  for (int kk = 0; kk < 16; ++kk) {
    short8 bfr = *(const short8*)&Bs[l31][kk * 16 + h * 8];
#pragma unroll
    for (int mt = 0; mt < 2; ++mt) {
      short8 af = *(const short8*)(wbase + (size_t)mt * 32 * 256 + kk * 16);
      acc[mt] =
          __builtin_amdgcn_mfma_f32_32x32x16_bf16(af, bfr, acc[mt], 0, 0, 0);
    }
  }
  float aslope = a_p[0];
  float s = 0.f, q = 0.f;
#pragma unroll
  for (int mt = 0; mt < 2; ++mt) {
#pragma unroll
    for (int r = 0; r < 16; ++r) {
      int row = (r & 3) + 8 * (r >> 2) + 4 * h;
      int o = m0 + mt * 32 + row;
      float v = acc[mt][r] + pb[o];
      v = v >= 0.f ? v : aslope * v;
      acc[mt][r] = v;
      s += v;
      q += v * v;
    }
  }
  s += __shfl_xor(s, 32, 64);
  q += __shfl_xor(q, 32, 64);
  if (h == 0) {
    lnS[wv][l31] = s;
    lnQ[wv][l31] = q;
  }
  __syncthreads();
  if (tid < 32) {
    float ss = 0.f, qq = 0.f;
#pragma unroll
    for (int w = 0; w < 8; ++w) {
      ss += lnS[w][tid];
      qq += lnQ[w][tid];
    }
    float mu = ss * (1.f / 512.f);
    float var = qq * (1.f / 512.f) - mu * mu;
    mu_s[tid] = mu;
    ri_s[tid] = rsqrtf(var + 1e-5f);
  }
  __syncthreads();
  float mu = mu_s[l31], ri = ri_s[l31];
  int tg = t0 + (l31 >> 3);
  int f = l31 & 7;
#pragma unroll
  for (int mt = 0; mt < 2; ++mt) {
#pragma unroll
    for (int r = 0; r < 16; ++r) {
      int row = (r & 3) + 8 * (r >> 2) + 4 * h;
      int o = m0 + mt * 32 + row;
      float v = (acc[mt][r] - mu) * ri * pg[o] + pe[o];
      short bv = bf16_rn(v);
      int head = o >> 6, lo = o & 63;
      int bh = b * 8 + head;
      if (lo < 32) {
        qkb[((size_t)(bh * 32 + lo) * 1024 + tg) * 8 + f] = bv;
      } else {
        vpb[((size_t)(bh * 128 + (tg >> 3)) * 256 + f * 32 + (lo - 32)) * 8 +
            (tg & 7)] = bv;
      }
    }
  }
}

// ---------------- attention: MFMA flash, 4 waves cooperate on 32 queries ---
// grid (x=bh, y=qtile) -> linear id % 8 == bh % 8 -> per-XCD K/V locality.
__global__ __launch_bounds__(256) void attn_mfma(const short* __restrict__ qkb,
                                                 const short* __restrict__ vpb,
                                                 short* __restrict__ ctxb) {
  __shared__ short pbuf[10][64 * 8];  // P A-frags, [frag][lane*8]
  __shared__ float wmax[4][32], wsum[4][32];
  int bh = blockIdx.x;
  int qt0 = blockIdx.y * 32;
  int tid = threadIdx.x;
  int wv = tid >> 6, lane = tid & 63;
  int l31 = lane & 31, h = lane >> 5;
  int b = bh >> 3, hh = bh & 7;
  const short* qbase = qkb + (size_t)bh * 32 * 1024 * 8;
  short8 qf[8];
#pragma unroll
  for (int kk = 0; kk < 8; ++kk) {
    int qc = 2 * kk + h;
    qf[kk] = *(const short8*)(qbase + ((size_t)qc * 1024 + qt0 + l31) * 8);
  }
  int ks_lo = qt0 > 100 ? ((qt0 - 100) & ~31) : 0;
  int kt_n = (qt0 + 32 - ks_lo) >> 5;  // 1..5 (block-uniform)
  int kt0 = wv, kt1 = wv + 4;
  bool has0 = kt0 < kt_n, has1 = kt1 < kt_n;
  int q_t = qt0 + l31;
  f32x16 S0, S1;
  float pm = -INFINITY;
  if (has0) {
#pragma unroll
    for (int r = 0; r < 16; ++r) S0[r] = 0.f;
    int sb = ks_lo + kt0 * 32;
#pragma unroll
    for (int kk = 0; kk < 8; ++kk) {
      int kc = 16 + 2 * kk + h;
      short8 kf = *(const short8*)(qbase + ((size_t)kc * 1024 + sb + l31) * 8);
      S0 = __builtin_amdgcn_mfma_f32_32x32x16_bf16(kf, qf[kk], S0, 0, 0, 0);
    }
#pragma unroll
    for (int r = 0; r < 16; ++r) {
      int s = sb + (r & 3) + 8 * (r >> 2) + 4 * h;
      float v = S0[r] * 0.08838834764831843f;
      bool ok = (s <= q_t) && (s + 100 >= q_t);
      v = ok ? v : -INFINITY;
      S0[r] = v;
      pm = fmaxf(pm, v);
    }
  }
  if (has1) {
#pragma unroll
    for (int r = 0; r < 16; ++r) S1[r] = 0.f;
    int sb = ks_lo + kt1 * 32;
#pragma unroll
    for (int kk = 0; kk < 8; ++kk) {
      int kc = 16 + 2 * kk + h;
      short8 kf = *(const short8*)(qbase + ((size_t)kc * 1024 + sb + l31) * 8);
      S1 = __builtin_amdgcn_mfma_f32_32x32x16_bf16(kf, qf[kk], S1, 0, 0, 0);
    }
#pragma unroll
    for (int r = 0; r < 16; ++r) {
      int s = sb + (r & 3) + 8 * (r >> 2) + 4 * h;
      float v = S1[r] * 0.08838834764831843f;
      bool ok = (s <= q_t) && (s + 100 >= q_t);
      v = ok ? v : -INFINITY;
      S1[r] = v;
      pm = fmaxf(pm, v);
    }
  }
  pm = fmaxf(pm, __shfl_xor(pm, 32, 64));
  if (h == 0) wmax[wv][l31] = pm;
  __syncthreads();
  float gm = fmaxf(fmaxf(wmax[0][l31], wmax[1][l31]),
                   fmaxf(wmax[2][l31], wmax[3][l31]));
  float ws = 0.f;
  if (has0) {
#pragma unroll
    for (int r = 0; r < 16; ++r) {
      float e = __expf(S0[r] - gm);
      S0[r] = e;
      ws += e;
    }
  }
  if (has1) {
#pragma unroll
    for (int r = 0; r < 16; ++r) {
      float e = __expf(S1[r] - gm);
      S1[r] = e;
      ws += e;
    }
  }
  ws += __shfl_xor(ws, 32, 64);
  if (h == 0) wsum[wv][l31] = ws;
  __syncthreads();
  float inv =
      1.f / (wsum[0][l31] + wsum[1][l31] + wsum[2][l31] + wsum[3][l31]);
  if (has0) {
#pragma unroll
    for (int ks2 = 0; ks2 < 2; ++ks2) {
      short tmp8[8];
#pragma unroll
      for (int jj = 0; jj < 4; ++jj) {
        int rA = 8 * ks2 + jj, rB = rA + 4;
        short a16 = bf16_rn(S0[rA] * inv);
        short b16 = bf16_rn(S0[rB] * inv);
        int pk = (int)(unsigned short)a16 | (((int)b16) << 16);
        int xp = __shfl_xor(pk, 32, 64);
        tmp8[jj] = h == 0 ? a16 : (short)(xp >> 16);
        tmp8[4 + jj] = h == 0 ? (short)(xp & 0xffff) : b16;
      }
      *(short8*)&pbuf[kt0 * 2 + ks2][lane * 8] = *(short8*)tmp8;
    }
  }
  if (has1) {
#pragma unroll
    for (int ks2 = 0; ks2 < 2; ++ks2) {
      short tmp8[8];
#pragma unroll
      for (int jj = 0; jj < 4; ++jj) {
        int rA = 8 * ks2 + jj, rB = rA + 4;
        short a16 = bf16_rn(S1[rA] * inv);
        short b16 = bf16_rn(S1[rB] * inv);
        int pk = (int)(unsigned short)a16 | (((int)b16) << 16);
        int xp = __shfl_xor(pk, 32, 64);
        tmp8[jj] = h == 0 ? a16 : (short)(xp >> 16);
        tmp8[4 + jj] = h == 0 ? (short)(xp & 0xffff) : b16;
      }
      *(short8*)&pbuf[kt1 * 2 + ks2][lane * 8] = *(short8*)tmp8;
    }
  }
  __syncthreads();
  const short* vbase = vpb + (size_t)bh * 128 * 256 * 8;
#pragma unroll
  for (int j = 0; j < 2; ++j) {
    int nt = wv * 2 + j;
    f32x16 acc;
#pragma unroll
    for (int r = 0; r < 16; ++r) acc[r] = 0.f;
    for (int kt = 0; kt < kt_n; ++kt) {
#pragma unroll
      for (int ks2 = 0; ks2 < 2; ++ks2) {
        short8 pfr = *(const short8*)&pbuf[kt * 2 + ks2][lane * 8];
        int sb = ks_lo + kt * 32 + ks2 * 16 + h * 8;
        short8 vf = *(const short8*)(vbase +
                                     ((size_t)(sb >> 3) * 256 + nt * 32 + l31) * 8);
        acc = __builtin_amdgcn_mfma_f32_32x32x16_bf16(pfr, vf, acc, 0, 0, 0);
      }
    }
    short* crow = ctxb + ((size_t)(b * 8 + nt) * T_DIM) * 256 + hh * 32 + l31;
#pragma unroll
    for (int r = 0; r < 16; ++r) {
      int t = qt0 + (r & 3) + 8 * (r >> 2) + 4 * h;
      if (t < T_DIM) crow[(size_t)t * 256] = bf16_rn(acc[r]);
    }
  }
}

// ---------------- proj: MFMA GEMM M=256 K=256 Ntile=32, 8 waves ------------
// grid 1024: id = tb*32 + bf  ->  id % 8 == bf % 8 (per-XCD ctx locality)
__global__ __launch_bounds__(512) void proj_mfma(
    const short* __restrict__ ctxb, const short* __restrict__ wb,
    const float* __restrict__ bias, const float* __restrict__ a_p,
    const float* __restrict__ gam, const float* __restrict__ bet,
    float* __restrict__ out) {
  __shared__ short Bs[32][264];
  __shared__ float lnS[8][32], lnQ[8][32];
  __shared__ float mu_s[32], ri_s[32];
  __shared__ float pb[256], pg[256], pe[256];
  int tid = threadIdx.x;
  int blk = blockIdx.x;
  int bf = blk & 31, tb = blk >> 5;
  int b = bf >> 3, f = bf & 7;
  int t0 = tb * 32;
  if (tid < 256) {
    pb[tid] = bias[tid];
    pg[tid] = gam[tid];
    pe[tid] = bet[tid];
  }
  {
    int row = tid >> 4, seg = (tid & 15) * 16;
    int t = t0 + row;
    if (t < T_DIM) {
      const short8* src =
          (const short8*)(ctxb + ((size_t)bf * T_DIM + t) * 256 + seg);
      *(short8*)&Bs[row][seg] = src[0];
      *(short8*)&Bs[row][seg + 8] = src[1];
    } else {
      short8 z = {0, 0, 0, 0, 0, 0, 0, 0};
      *(short8*)&Bs[row][seg] = z;
      *(short8*)&Bs[row][seg + 8] = z;
    }
  }
  __syncthreads();
  int lane = tid & 63, wv = tid >> 6;  // wv 0..7
  int h = lane >> 5, l31 = lane & 31;
  int m0 = wv * 32;
  f32x16 acc;
#pragma unroll
  for (int r = 0; r < 16; ++r) acc[r] = 0.f;
  const short* wbase = wb + ((size_t)(m0 + l31)) * 256 + h * 8;
#pragma unroll
  for (int kk = 0; kk < 16; ++kk) {
    short8 bfr = *(const short8*)&Bs[l31][kk * 16 + h * 8];
    short8 af = *(const short8*)(wbase + kk * 16);
    acc = __builtin_amdgcn_mfma_f32_32x32x16_bf16(af, bfr, acc, 0, 0, 0);
  }
  float aslope = a_p[0];
  float s = 0.f, q = 0.f;
#pragma unroll
  for (int r = 0; r < 16; ++r) {
    int row = (r & 3) + 8 * (r >> 2) + 4 * h;
    int o = m0 + row;
    float v = acc[r] + pb[o];
    v = v >= 0.f ? v : aslope * v;
    acc[r] = v;
    s += v;
    q += v * v;
  }
  s += __shfl_xor(s, 32, 64);
  q += __shfl_xor(q, 32, 64);
  if (h == 0) {
    lnS[wv][l31] = s;
    lnQ[wv][l31] = q;
  }
  __syncthreads();
  if (tid < 32) {
    float ss = 0.f, qq = 0.f;
#pragma unroll
    for (int w = 0; w < 8; ++w) {
      ss += lnS[w][tid];
      qq += lnQ[w][tid];
    }
    float mu = ss * (1.f / 256.f);
    float var = qq * (1.f / 256.f) - mu * mu;
    mu_s[tid] = mu;
    ri_s[tid] = rsqrtf(var + 1e-5f);
  }
  __syncthreads();
  float mu = mu_s[l31], ri = ri_s[l31];
  int t = t0 + l31;
  if (t < T_DIM) {
#pragma unroll
    for (int r = 0; r < 16; ++r) {
      int row = (r & 3) + 8 * (r >> 2) + 4 * h;
      int o = m0 + row;
      float v = (acc[r] - mu) * ri * pg[o] + pe[o];
      out[((size_t)(b * 2048 + o * 8 + f)) * T_DIM + t] = v;
    }
  }
}

extern "C" void kernel_launch(void* const* d_in, const int* in_sizes, int n_in,
                              void* d_out, int out_size, void* d_ws,
                              size_t ws_size, hipStream_t stream) {
  const float* x = (const float*)d_in[0];
  const float* w_qkv = (const float*)d_in[1];
  const float* b_qkv = (const float*)d_in[2];
  const float* a_qkv = (const float*)d_in[3];
  const float* g_qkv = (const float*)d_in[4];
  const float* be_qkv = (const float*)d_in[5];
  const float* w_proj = (const float*)d_in[6];
  const float* b_proj = (const float*)d_in[7];
  const float* a_proj = (const float*)d_in[8];
  const float* g_proj = (const float*)d_in[9];
  const float* be_proj = (const float*)d_in[10];
  float* out = (float*)d_out;

  short* wqb = (short*)d_ws;            // 512*256
  short* wpb = wqb + 131072;            // 256*256
  short* qkb = wpb + 65536;             // 32*32*1024*8
  short* vpb = qkb + (size_t)8388608;   // 32*128*256*8
  short* ctxb = vpb + (size_t)8388608;  // 32000*256

  prep_w<<<768, 256, 0, stream>>>(w_qkv, w_proj, wqb, wpb);
  qkv_mfma<<<1000, 512, 0, stream>>>(x, wqb, b_qkv, a_qkv, g_qkv, be_qkv,
                                     qkb, vpb);
  attn_mfma<<<dim3(32, 32), 256, 0, stream>>>(qkb, vpb, ctxb);
  proj_mfma<<<1024, 512, 0, stream>>>(ctxb, wpb, b_proj, a_proj, g_proj,
                                      be_proj, out);
}

// Round 8
// 184.762 us; speedup vs baseline: 1.0637x; 1.0637x over previous
//
#include <hip/hip_runtime.h>
#include <math.h>

#define T_DIM 1000

typedef __attribute__((ext_vector_type(8))) short short8;
typedef __attribute__((ext_vector_type(16))) float f32x16;

static __device__ __forceinline__ short bf16_rn(float f) {
  union { float f; unsigned u; } v;
  v.f = f;
  unsigned r = v.u + 0x7fffu + ((v.u >> 16) & 1u);
  return (short)(r >> 16);
}

// weight conversion, both matrices in one launch (grid 768)
__global__ __launch_bounds__(256) void prep_w(const float* __restrict__ wq,
                                              const float* __restrict__ wp,
                                              short* __restrict__ wqb,
                                              short* __restrict__ wpb) {
  int i = blockIdx.x * 256 + threadIdx.x;
  if (i < 131072) wqb[i] = bf16_rn(wq[i]);
  int j = i - 131072;
  if (j >= 0 && j < 65536) wpb[j] = bf16_rn(wp[j]);
}

// x[b][c][f][t] fp32 -> xbt[(b*T+t)*8+f][256] bf16  (coalesced both sides)
__global__ __launch_bounds__(256) void xpose_x(const float* __restrict__ x,
                                               short* __restrict__ xbt) {
  __shared__ float tile[64][65];
  int bf = blockIdx.z;  // b*8+f
  int b = bf >> 3, f = bf & 7;
  int c0 = blockIdx.x * 64, t0 = blockIdx.y * 64;
  int tid = threadIdx.x;
  int tc = tid & 63;
  int t = t0 + tc;
  if (t < T_DIM) {
    int sg = tid >> 6;  // 0..3
#pragma unroll
    for (int i = 0; i < 16; ++i) {
      int cr = i * 4 + sg;
      tile[cr][tc] = x[((size_t)(b * 256 + c0 + cr) * 8 + f) * T_DIM + t];
    }
  }
  __syncthreads();
  int tr = tid >> 2, cg = (tid & 3) * 16;
  int tt = t0 + tr;
  if (tt < T_DIM) {
    short tmp[16];
#pragma unroll
    for (int i = 0; i < 16; ++i) tmp[i] = bf16_rn(tile[cg + i][tr]);
    short* dst = xbt + ((size_t)((b * T_DIM + tt) * 8 + f)) * 256 + c0 + cg;
    *(short8*)dst = *(short8*)tmp;
    *(short8*)(dst + 8) = *(short8*)(tmp + 8);
  }
}

// ---------------- QKV: MFMA GEMM M=512 K=256 Ntile=32, 8 waves -------------
// grid 1000 (b, t-tile of 4); staging = 16 KB contiguous from xbt.
__global__ __launch_bounds__(512) void qkv_mfma(
    const short* __restrict__ xbt, const short* __restrict__ wb,
    const float* __restrict__ bias, const float* __restrict__ a_p,
    const float* __restrict__ gam, const float* __restrict__ bet,
    short* __restrict__ qkb, short* __restrict__ vpb) {
  __shared__ short Bs[32][264];
  __shared__ float lnS[8][32], lnQ[8][32];
  __shared__ float mu_s[32], ri_s[32];
  __shared__ float pb[512], pg[512], pe[512];
  int tid = threadIdx.x;
  int blk = blockIdx.x;
  int b = blk / 250;
  int t0 = (blk % 250) * 4;
  pb[tid] = bias[tid];
  pg[tid] = gam[tid];
  pe[tid] = bet[tid];
  {
    int row = tid >> 4, col = (tid & 15) * 16;
    const short8* src = (const short8*)(
        xbt + (size_t)(b * T_DIM + t0) * 8 * 256 + row * 256 + col);
    *(short8*)&Bs[row][col] = src[0];
    *(short8*)&Bs[row][col + 8] = src[1];
  }
  __syncthreads();
  int lane = tid & 63, wv = tid >> 6;  // wv 0..7
  int h = lane >> 5, l31 = lane & 31;
  int m0 = wv * 64;
  f32x16 acc[2];
#pragma unroll
  for (int mt = 0; mt < 2; ++mt)
#pragma unroll
    for (int r = 0; r < 16; ++r) acc[mt][r] = 0.f;
  const short* wbase = wb + ((size_t)(m0 + l31)) * 256 + h * 8;
#pragma unroll
  for (int kk = 0; kk < 16; ++kk) {
    short8 bfr = *(const short8*)&Bs[l31][kk * 16 + h * 8];
#pragma unroll
    for (int mt = 0; mt < 2; ++mt) {
      short8 af = *(const short8*)(wbase + (size_t)mt * 32 * 256 + kk * 16);
      acc[mt] =
          __builtin_amdgcn_mfma_f32_32x32x16_bf16(af, bfr, acc[mt], 0, 0, 0);
    }
  }
  float aslope = a_p[0];
  float s = 0.f, q = 0.f;
#pragma unroll
  for (int mt = 0; mt < 2; ++mt) {
#pragma unroll
    for (int r = 0; r < 16; ++r) {
      int row = (r & 3) + 8 * (r >> 2) + 4 * h;
      int o = m0 + mt * 32 + row;
      float v = acc[mt][r] + pb[o];
      v = v >= 0.f ? v : aslope * v;
      acc[mt][r] = v;
      s += v;
      q += v * v;
    }
  }
  s += __shfl_xor(s, 32, 64);
  q += __shfl_xor(q, 32, 64);
  if (h == 0) {
    lnS[wv][l31] = s;
    lnQ[wv][l31] = q;
  }
  __syncthreads();
  if (tid < 32) {
    float ss = 0.f, qq = 0.f;
#pragma unroll
    for (int w = 0; w < 8; ++w) {
      ss += lnS[w][tid];
      qq += lnQ[w][tid];
    }
    float mu = ss * (1.f / 512.f);
    float var = qq * (1.f / 512.f) - mu * mu;
    mu_s[tid] = mu;
    ri_s[tid] = rsqrtf(var + 1e-5f);
  }
  __syncthreads();
  float mu = mu_s[l31], ri = ri_s[l31];
  int tg = t0 + (l31 >> 3);
  int f = l31 & 7;
#pragma unroll
  for (int mt = 0; mt < 2; ++mt) {
#pragma unroll
    for (int r = 0; r < 16; ++r) {
      int row = (r & 3) + 8 * (r >> 2) + 4 * h;
      int o = m0 + mt * 32 + row;
      float v = (acc[mt][r] - mu) * ri * pg[o] + pe[o];
      short bv = bf16_rn(v);
      int head = o >> 6, lo = o & 63;
      int bh = b * 8 + head;
      if (lo < 32) {
        qkb[((size_t)(bh * 32 + lo) * 1024 + tg) * 8 + f] = bv;
      } else {
        vpb[((size_t)(bh * 128 + (tg >> 3)) * 256 + f * 32 + (lo - 32)) * 8 +
            (tg & 7)] = bv;
      }
    }
  }
}

// ---------------- attention: MFMA flash, 4 waves cooperate on 32 queries ---
// grid (x=bh, y=qtile) -> linear id % 8 == bh % 8 -> per-XCD K/V locality.
__global__ __launch_bounds__(256) void attn_mfma(const short* __restrict__ qkb,
                                                 const short* __restrict__ vpb,
                                                 short* __restrict__ ctxb) {
  __shared__ short pbuf[10][64 * 8];  // P A-frags, [frag][lane*8]
  __shared__ float wmax[4][32], wsum[4][32];
  int bh = blockIdx.x;
  int qt0 = blockIdx.y * 32;
  int tid = threadIdx.x;
  int wv = tid >> 6, lane = tid & 63;
  int l31 = lane & 31, h = lane >> 5;
  int b = bh >> 3, hh = bh & 7;
  const short* qbase = qkb + (size_t)bh * 32 * 1024 * 8;
  short8 qf[8];
#pragma unroll
  for (int kk = 0; kk < 8; ++kk) {
    int qc = 2 * kk + h;
    qf[kk] = *(const short8*)(qbase + ((size_t)qc * 1024 + qt0 + l31) * 8);
  }
  int ks_lo = qt0 > 100 ? ((qt0 - 100) & ~31) : 0;
  int kt_n = (qt0 + 32 - ks_lo) >> 5;  // 1..5 (block-uniform)
  int kt0 = wv, kt1 = wv + 4;
  bool has0 = kt0 < kt_n, has1 = kt1 < kt_n;
  int q_t = qt0 + l31;
  f32x16 S0, S1;
  float pm = -INFINITY;
  if (has0) {
#pragma unroll
    for (int r = 0; r < 16; ++r) S0[r] = 0.f;
    int sb = ks_lo + kt0 * 32;
#pragma unroll
    for (int kk = 0; kk < 8; ++kk) {
      int kc = 16 + 2 * kk + h;
      short8 kf = *(const short8*)(qbase + ((size_t)kc * 1024 + sb + l31) * 8);
      S0 = __builtin_amdgcn_mfma_f32_32x32x16_bf16(kf, qf[kk], S0, 0, 0, 0);
    }
#pragma unroll
    for (int r = 0; r < 16; ++r) {
      int s = sb + (r & 3) + 8 * (r >> 2) + 4 * h;
      float v = S0[r] * 0.08838834764831843f;
      bool ok = (s <= q_t) && (s + 100 >= q_t);
      v = ok ? v : -INFINITY;
      S0[r] = v;
      pm = fmaxf(pm, v);
    }
  }
  if (has1) {
#pragma unroll
    for (int r = 0; r < 16; ++r) S1[r] = 0.f;
    int sb = ks_lo + kt1 * 32;
#pragma unroll
    for (int kk = 0; kk < 8; ++kk) {
      int kc = 16 + 2 * kk + h;
      short8 kf = *(const short8*)(qbase + ((size_t)kc * 1024 + sb + l31) * 8);
      S1 = __builtin_amdgcn_mfma_f32_32x32x16_bf16(kf, qf[kk], S1, 0, 0, 0);
    }
#pragma unroll
    for (int r = 0; r < 16; ++r) {
      int s = sb + (r & 3) + 8 * (r >> 2) + 4 * h;
      float v = S1[r] * 0.08838834764831843f;
      bool ok = (s <= q_t) && (s + 100 >= q_t);
      v = ok ? v : -INFINITY;
      S1[r] = v;
      pm = fmaxf(pm, v);
    }
  }
  pm = fmaxf(pm, __shfl_xor(pm, 32, 64));
  if (h == 0) wmax[wv][l31] = pm;
  __syncthreads();
  float gm = fmaxf(fmaxf(wmax[0][l31], wmax[1][l31]),
                   fmaxf(wmax[2][l31], wmax[3][l31]));
  float ws = 0.f;
  if (has0) {
#pragma unroll
    for (int r = 0; r < 16; ++r) {
      float e = __expf(S0[r] - gm);
      S0[r] = e;
      ws += e;
    }
  }
  if (has1) {
#pragma unroll
    for (int r = 0; r < 16; ++r) {
      float e = __expf(S1[r] - gm);
      S1[r] = e;
      ws += e;
    }
  }
  ws += __shfl_xor(ws, 32, 64);
  if (h == 0) wsum[wv][l31] = ws;
  __syncthreads();
  float inv =
      1.f / (wsum[0][l31] + wsum[1][l31] + wsum[2][l31] + wsum[3][l31]);
  if (has0) {
#pragma unroll
    for (int ks2 = 0; ks2 < 2; ++ks2) {
      short tmp8[8];
#pragma unroll
      for (int jj = 0; jj < 4; ++jj) {
        int rA = 8 * ks2 + jj, rB = rA + 4;
        short a16 = bf16_rn(S0[rA] * inv);
        short b16 = bf16_rn(S0[rB] * inv);
        int pk = (int)(unsigned short)a16 | (((int)b16) << 16);
        int xp = __shfl_xor(pk, 32, 64);
        tmp8[jj] = h == 0 ? a16 : (short)(xp >> 16);
        tmp8[4 + jj] = h == 0 ? (short)(xp & 0xffff) : b16;
      }
      *(short8*)&pbuf[kt0 * 2 + ks2][lane * 8] = *(short8*)tmp8;
    }
  }
  if (has1) {
#pragma unroll
    for (int ks2 = 0; ks2 < 2; ++ks2) {
      short tmp8[8];
#pragma unroll
      for (int jj = 0; jj < 4; ++jj) {
        int rA = 8 * ks2 + jj, rB = rA + 4;
        short a16 = bf16_rn(S1[rA] * inv);
        short b16 = bf16_rn(S1[rB] * inv);
        int pk = (int)(unsigned short)a16 | (((int)b16) << 16);
        int xp = __shfl_xor(pk, 32, 64);
        tmp8[jj] = h == 0 ? a16 : (short)(xp >> 16);
        tmp8[4 + jj] = h == 0 ? (short)(xp & 0xffff) : b16;
      }
      *(short8*)&pbuf[kt1 * 2 + ks2][lane * 8] = *(short8*)tmp8;
    }
  }
  __syncthreads();
  const short* vbase = vpb + (size_t)bh * 128 * 256 * 8;
#pragma unroll
  for (int j = 0; j < 2; ++j) {
    int nt = wv * 2 + j;
    f32x16 acc;
#pragma unroll
    for (int r = 0; r < 16; ++r) acc[r] = 0.f;
    for (int kt = 0; kt < kt_n; ++kt) {
#pragma unroll
      for (int ks2 = 0; ks2 < 2; ++ks2) {
        short8 pfr = *(const short8*)&pbuf[kt * 2 + ks2][lane * 8];
        int sb = ks_lo + kt * 32 + ks2 * 16 + h * 8;
        short8 vf = *(const short8*)(vbase +
                                     ((size_t)(sb >> 3) * 256 + nt * 32 + l31) * 8);
        acc = __builtin_amdgcn_mfma_f32_32x32x16_bf16(pfr, vf, acc, 0, 0, 0);
      }
    }
    short* crow = ctxb + ((size_t)(b * 8 + nt) * T_DIM) * 256 + hh * 32 + l31;
#pragma unroll
    for (int r = 0; r < 16; ++r) {
      int t = qt0 + (r & 3) + 8 * (r >> 2) + 4 * h;
      if (t < T_DIM) crow[(size_t)t * 256] = bf16_rn(acc[r]);
    }
  }
}

// ---------------- proj: MFMA GEMM M=256 K=256 Ntile=32, 8 waves ------------
// grid 1024: id = tb*32 + bf  ->  id % 8 == bf % 8 (per-XCD ctx locality)
__global__ __launch_bounds__(512) void proj_mfma(
    const short* __restrict__ ctxb, const short* __restrict__ wb,
    const float* __restrict__ bias, const float* __restrict__ a_p,
    const float* __restrict__ gam, const float* __restrict__ bet,
    float* __restrict__ out) {
  __shared__ short Bs[32][264];
  __shared__ float lnS[8][32], lnQ[8][32];
  __shared__ float mu_s[32], ri_s[32];
  __shared__ float pb[256], pg[256], pe[256];
  int tid = threadIdx.x;
  int blk = blockIdx.x;
  int bf = blk & 31, tb = blk >> 5;
  int b = bf >> 3, f = bf & 7;
  int t0 = tb * 32;
  if (tid < 256) {
    pb[tid] = bias[tid];
    pg[tid] = gam[tid];
    pe[tid] = bet[tid];
  }
  {
    int row = tid >> 4, seg = (tid & 15) * 16;
    int t = t0 + row;
    if (t < T_DIM) {
      const short8* src =
          (const short8*)(ctxb + ((size_t)bf * T_DIM + t) * 256 + seg);
      *(short8*)&Bs[row][seg] = src[0];
      *(short8*)&Bs[row][seg + 8] = src[1];
    } else {
      short8 z = {0, 0, 0, 0, 0, 0, 0, 0};
      *(short8*)&Bs[row][seg] = z;
      *(short8*)&Bs[row][seg + 8] = z;
    }
  }
  __syncthreads();
  int lane = tid & 63, wv = tid >> 6;  // wv 0..7
  int h = lane >> 5, l31 = lane & 31;
  int m0 = wv * 32;
  f32x16 acc;
#pragma unroll
  for (int r = 0; r < 16; ++r) acc[r] = 0.f;
  const short* wbase = wb + ((size_t)(m0 + l31)) * 256 + h * 8;
#pragma unroll
  for (int kk = 0; kk < 16; ++kk) {
    short8 bfr = *(const short8*)&Bs[l31][kk * 16 + h * 8];
    short8 af = *(const short8*)(wbase + kk * 16);
    acc = __builtin_amdgcn_mfma_f32_32x32x16_bf16(af, bfr, acc, 0, 0, 0);
  }
  float aslope = a_p[0];
  float s = 0.f, q = 0.f;
#pragma unroll
  for (int r = 0; r < 16; ++r) {
    int row = (r & 3) + 8 * (r >> 2) + 4 * h;
    int o = m0 + row;
    float v = acc[r] + pb[o];
    v = v >= 0.f ? v : aslope * v;
    acc[r] = v;
    s += v;
    q += v * v;
  }
  s += __shfl_xor(s, 32, 64);
  q += __shfl_xor(q, 32, 64);
  if (h == 0) {
    lnS[wv][l31] = s;
    lnQ[wv][l31] = q;
  }
  __syncthreads();
  if (tid < 32) {
    float ss = 0.f, qq = 0.f;
#pragma unroll
    for (int w = 0; w < 8; ++w) {
      ss += lnS[w][tid];
      qq += lnQ[w][tid];
    }
    float mu = ss * (1.f / 256.f);
    float var = qq * (1.f / 256.f) - mu * mu;
    mu_s[tid] = mu;
    ri_s[tid] = rsqrtf(var + 1e-5f);
  }
  __syncthreads();
  float mu = mu_s[l31], ri = ri_s[l31];
  int t = t0 + l31;
  if (t < T_DIM) {
#pragma unroll
    for (int r = 0; r < 16; ++r) {
      int row = (r & 3) + 8 * (r >> 2) + 4 * h;
      int o = m0 + row;
      float v = (acc[r] - mu) * ri * pg[o] + pe[o];
      out[((size_t)(b * 2048 + o * 8 + f)) * T_DIM + t] = v;
    }
  }
}

extern "C" void kernel_launch(void* const* d_in, const int* in_sizes, int n_in,
                              void* d_out, int out_size, void* d_ws,
                              size_t ws_size, hipStream_t stream) {
  const float* x = (const float*)d_in[0];
  const float* w_qkv = (const float*)d_in[1];
  const float* b_qkv = (const float*)d_in[2];
  const float* a_qkv = (const float*)d_in[3];
  const float* g_qkv = (const float*)d_in[4];
  const float* be_qkv = (const float*)d_in[5];
  const float* w_proj = (const float*)d_in[6];
  const float* b_proj = (const float*)d_in[7];
  const float* a_proj = (const float*)d_in[8];
  const float* g_proj = (const float*)d_in[9];
  const float* be_proj = (const float*)d_in[10];
  float* out = (float*)d_out;

  short* wqb = (short*)d_ws;            // 512*256
  short* wpb = wqb + 131072;            // 256*256
  short* xbt = wpb + 65536;             // 32000*256
  short* qkb = xbt + (size_t)8192000;   // 32*32*1024*8
  short* vpb = qkb + (size_t)8388608;   // 32*128*256*8
  short* ctxb = vpb + (size_t)8388608;  // 32000*256

  prep_w<<<768, 256, 0, stream>>>(w_qkv, w_proj, wqb, wpb);
  xpose_x<<<dim3(4, 16, 32), 256, 0, stream>>>(x, xbt);
  qkv_mfma<<<1000, 512, 0, stream>>>(xbt, wqb, b_qkv, a_qkv, g_qkv, be_qkv,
                                     qkb, vpb);
  attn_mfma<<<dim3(32, 32), 256, 0, stream>>>(qkb, vpb, ctxb);
  proj_mfma<<<1024, 512, 0, stream>>>(ctxb, wpb, b_proj, a_proj, g_proj,
                                      be_proj, out);
}

// Round 9
// 159.562 us; speedup vs baseline: 1.2317x; 1.1579x over previous
//
#include <hip/hip_runtime.h>
#include <math.h>

#define T_DIM 1000

typedef __attribute__((ext_vector_type(8))) short short8;
typedef __attribute__((ext_vector_type(16))) float f32x16;

static __device__ __forceinline__ short bf16_rn(float f) {
  union { float f; unsigned u; } v;
  v.f = f;
  unsigned r = v.u + 0x7fffu + ((v.u >> 16) & 1u);
  return (short)(r >> 16);
}

// weight cvt + swizzle into MFMA A-fragment order:
// dst[(((o>>5)*16 + (c>>4))*2 + ((c>>3)&1))*32 + (o&31)][c&7]
// -> a wave's A-frag load is 64 lanes x contiguous 16B (fully coalesced).
__global__ __launch_bounds__(256) void prep_w(const float* __restrict__ wq,
                                              const float* __restrict__ wp,
                                              short* __restrict__ wqs,
                                              short* __restrict__ wps) {
  int i = blockIdx.x * 256 + threadIdx.x;
  if (i < 131072) {
    int o = i >> 8, c = i & 255;
    int idx =
        ((((o >> 5) * 16 + (c >> 4)) * 2 + ((c >> 3) & 1)) * 32 + (o & 31)) * 8 +
        (c & 7);
    wqs[idx] = bf16_rn(wq[i]);
  }
  int j = i - 131072;
  if (j >= 0 && j < 65536) {
    int o = j >> 8, c = j & 255;
    int idx =
        ((((o >> 5) * 16 + (c >> 4)) * 2 + ((c >> 3) & 1)) * 32 + (o & 31)) * 8 +
        (c & 7);
    wps[idx] = bf16_rn(wp[j]);
  }
}

// x[b][c][f][t] fp32 -> xbt[(b*T+t)*8+f][256] bf16  (coalesced both sides)
__global__ __launch_bounds__(256) void xpose_x(const float* __restrict__ x,
                                               short* __restrict__ xbt) {
  __shared__ float tile[64][65];
  int bf = blockIdx.z;  // b*8+f
  int b = bf >> 3, f = bf & 7;
  int c0 = blockIdx.x * 64, t0 = blockIdx.y * 64;
  int tid = threadIdx.x;
  int tc = tid & 63;
  int t = t0 + tc;
  if (t < T_DIM) {
    int sg = tid >> 6;  // 0..3
#pragma unroll
    for (int i = 0; i < 16; ++i) {
      int cr = i * 4 + sg;
      tile[cr][tc] = x[((size_t)(b * 256 + c0 + cr) * 8 + f) * T_DIM + t];
    }
  }
  __syncthreads();
  int tr = tid >> 2, cg = (tid & 3) * 16;
  int tt = t0 + tr;
  if (tt < T_DIM) {
    short tmp[16];
#pragma unroll
    for (int i = 0; i < 16; ++i) tmp[i] = bf16_rn(tile[cg + i][tr]);
    short* dst = xbt + ((size_t)((b * T_DIM + tt) * 8 + f)) * 256 + c0 + cg;
    *(short8*)dst = *(short8*)tmp;
    *(short8*)(dst + 8) = *(short8*)(tmp + 8);
  }
}

// ---------------- QKV: MFMA GEMM M=512 K=256 Ntile=32, 8 waves -------------
// grid 1000 (b, t-tile of 4); staging = 16 KB contiguous from xbt.
// w in fragment-order: addr = mblk*8192 + kk*512 + h*256 + l31*8
__global__ __launch_bounds__(512) void qkv_mfma(
    const short* __restrict__ xbt, const short* __restrict__ wb,
    const float* __restrict__ bias, const float* __restrict__ a_p,
    const float* __restrict__ gam, const float* __restrict__ bet,
    short* __restrict__ qkb, short* __restrict__ vpb) {
  __shared__ short Bs[32][264];
  __shared__ float lnS[8][32], lnQ[8][32];
  __shared__ float mu_s[32], ri_s[32];
  __shared__ float pb[512], pg[512], pe[512];
  int tid = threadIdx.x;
  int blk = blockIdx.x;
  int b = blk / 250;
  int t0 = (blk % 250) * 4;
  pb[tid] = bias[tid];
  pg[tid] = gam[tid];
  pe[tid] = bet[tid];
  {
    int row = tid >> 4, col = (tid & 15) * 16;
    const short8* src = (const short8*)(
        xbt + (size_t)(b * T_DIM + t0) * 8 * 256 + row * 256 + col);
    *(short8*)&Bs[row][col] = src[0];
    *(short8*)&Bs[row][col + 8] = src[1];
  }
  __syncthreads();
  int lane = tid & 63, wv = tid >> 6;  // wv 0..7
  int h = lane >> 5, l31 = lane & 31;
  int m0 = wv * 64;
  f32x16 acc[2];
#pragma unroll
  for (int mt = 0; mt < 2; ++mt)
#pragma unroll
    for (int r = 0; r < 16; ++r) acc[mt][r] = 0.f;
  const short* wfb = wb + (size_t)(wv * 2) * 8192 + h * 256 + l31 * 8;
#pragma unroll
  for (int kk = 0; kk < 16; ++kk) {
    short8 bfr = *(const short8*)&Bs[l31][kk * 16 + h * 8];
#pragma unroll
    for (int mt = 0; mt < 2; ++mt) {
      short8 af = *(const short8*)(wfb + mt * 8192 + kk * 512);
      acc[mt] =
          __builtin_amdgcn_mfma_f32_32x32x16_bf16(af, bfr, acc[mt], 0, 0, 0);
    }
  }
  float aslope = a_p[0];
  float s = 0.f, q = 0.f;
#pragma unroll
  for (int mt = 0; mt < 2; ++mt) {
#pragma unroll
    for (int r = 0; r < 16; ++r) {
      int row = (r & 3) + 8 * (r >> 2) + 4 * h;
      int o = m0 + mt * 32 + row;
      float v = acc[mt][r] + pb[o];
      v = v >= 0.f ? v : aslope * v;
      acc[mt][r] = v;
      s += v;
      q += v * v;
    }
  }
  s += __shfl_xor(s, 32, 64);
  q += __shfl_xor(q, 32, 64);
  if (h == 0) {
    lnS[wv][l31] = s;
    lnQ[wv][l31] = q;
  }
  __syncthreads();
  if (tid < 32) {
    float ss = 0.f, qq = 0.f;
#pragma unroll
    for (int w = 0; w < 8; ++w) {
      ss += lnS[w][tid];
      qq += lnQ[w][tid];
    }
    float mu = ss * (1.f / 512.f);
    float var = qq * (1.f / 512.f) - mu * mu;
    mu_s[tid] = mu;
    ri_s[tid] = rsqrtf(var + 1e-5f);
  }
  __syncthreads();
  float mu = mu_s[l31], ri = ri_s[l31];
  int tg = t0 + (l31 >> 3);
  int f = l31 & 7;
#pragma unroll
  for (int mt = 0; mt < 2; ++mt) {
#pragma unroll
    for (int r = 0; r < 16; ++r) {
      int row = (r & 3) + 8 * (r >> 2) + 4 * h;
      int o = m0 + mt * 32 + row;
      float v = (acc[mt][r] - mu) * ri * pg[o] + pe[o];
      short bv = bf16_rn(v);
      int head = o >> 6, lo = o & 63;
      int bh = b * 8 + head;
      if (lo < 32) {
        qkb[((size_t)(bh * 32 + lo) * 1024 + tg) * 8 + f] = bv;
      } else {
        vpb[((size_t)(bh * 128 + (tg >> 3)) * 256 + f * 32 + (lo - 32)) * 8 +
            (tg & 7)] = bv;
      }
    }
  }
}

// ---------------- attention: MFMA flash, 4 waves cooperate on 32 queries ---
// grid (x=bh, y=qtile) -> linear id % 8 == bh % 8 -> per-XCD K/V locality.
__global__ __launch_bounds__(256) void attn_mfma(const short* __restrict__ qkb,
                                                 const short* __restrict__ vpb,
                                                 short* __restrict__ ctxb) {
  __shared__ short pbuf[10][64 * 8];  // P A-frags, [frag][lane*8]
  __shared__ float wmax[4][32], wsum[4][32];
  int bh = blockIdx.x;
  int qt0 = blockIdx.y * 32;
  int tid = threadIdx.x;
  int wv = tid >> 6, lane = tid & 63;
  int l31 = lane & 31, h = lane >> 5;
  int b = bh >> 3, hh = bh & 7;
  const short* qbase = qkb + (size_t)bh * 32 * 1024 * 8;
  short8 qf[8];
#pragma unroll
  for (int kk = 0; kk < 8; ++kk) {
    int qc = 2 * kk + h;
    qf[kk] = *(const short8*)(qbase + ((size_t)qc * 1024 + qt0 + l31) * 8);
  }
  int ks_lo = qt0 > 100 ? ((qt0 - 100) & ~31) : 0;
  int kt_n = (qt0 + 32 - ks_lo) >> 5;  // 1..5 (block-uniform)
  int kt0 = wv, kt1 = wv + 4;
  bool has0 = kt0 < kt_n, has1 = kt1 < kt_n;
  int q_t = qt0 + l31;
  f32x16 S0, S1;
  float pm = -INFINITY;
  if (has0) {
#pragma unroll
    for (int r = 0; r < 16; ++r) S0[r] = 0.f;
    int sb = ks_lo + kt0 * 32;
#pragma unroll
    for (int kk = 0; kk < 8; ++kk) {
      int kc = 16 + 2 * kk + h;
      short8 kf = *(const short8*)(qbase + ((size_t)kc * 1024 + sb + l31) * 8);
      S0 = __builtin_amdgcn_mfma_f32_32x32x16_bf16(kf, qf[kk], S0, 0, 0, 0);
    }
#pragma unroll
    for (int r = 0; r < 16; ++r) {
      int s = sb + (r & 3) + 8 * (r >> 2) + 4 * h;
      float v = S0[r] * 0.08838834764831843f;
      bool ok = (s <= q_t) && (s + 100 >= q_t);
      v = ok ? v : -INFINITY;
      S0[r] = v;
      pm = fmaxf(pm, v);
    }
  }
  if (has1) {
#pragma unroll
    for (int r = 0; r < 16; ++r) S1[r] = 0.f;
    int sb = ks_lo + kt1 * 32;
#pragma unroll
    for (int kk = 0; kk < 8; ++kk) {
      int kc = 16 + 2 * kk + h;
      short8 kf = *(const short8*)(qbase + ((size_t)kc * 1024 + sb + l31) * 8);
      S1 = __builtin_amdgcn_mfma_f32_32x32x16_bf16(kf, qf[kk], S1, 0, 0, 0);
    }
#pragma unroll
    for (int r = 0; r < 16; ++r) {
      int s = sb + (r & 3) + 8 * (r >> 2) + 4 * h;
      float v = S1[r] * 0.08838834764831843f;
      bool ok = (s <= q_t) && (s + 100 >= q_t);
      v = ok ? v : -INFINITY;
      S1[r] = v;
      pm = fmaxf(pm, v);
    }
  }
  pm = fmaxf(pm, __shfl_xor(pm, 32, 64));
  if (h == 0) wmax[wv][l31] = pm;
  __syncthreads();
  float gm = fmaxf(fmaxf(wmax[0][l31], wmax[1][l31]),
                   fmaxf(wmax[2][l31], wmax[3][l31]));
  float ws = 0.f;
  if (has0) {
#pragma unroll
    for (int r = 0; r < 16; ++r) {
      float e = __expf(S0[r] - gm);
      S0[r] = e;
      ws += e;
    }
  }
  if (has1) {
#pragma unroll
    for (int r = 0; r < 16; ++r) {
      float e = __expf(S1[r] - gm);
      S1[r] = e;
      ws += e;
    }
  }
  ws += __shfl_xor(ws, 32, 64);
  if (h == 0) wsum[wv][l31] = ws;
  __syncthreads();
  float inv =
      1.f / (wsum[0][l31] + wsum[1][l31] + wsum[2][l31] + wsum[3][l31]);
  if (has0) {
#pragma unroll
    for (int ks2 = 0; ks2 < 2; ++ks2) {
      short tmp8[8];
#pragma unroll
      for (int jj = 0; jj < 4; ++jj) {
        int rA = 8 * ks2 + jj, rB = rA + 4;
        short a16 = bf16_rn(S0[rA] * inv);
        short b16 = bf16_rn(S0[rB] * inv);
        int pk = (int)(unsigned short)a16 | (((int)b16) << 16);
        int xp = __shfl_xor(pk, 32, 64);
        tmp8[jj] = h == 0 ? a16 : (short)(xp >> 16);
        tmp8[4 + jj] = h == 0 ? (short)(xp & 0xffff) : b16;
      }
      *(short8*)&pbuf[kt0 * 2 + ks2][lane * 8] = *(short8*)tmp8;
    }
  }
  if (has1) {
#pragma unroll
    for (int ks2 = 0; ks2 < 2; ++ks2) {
      short tmp8[8];
#pragma unroll
      for (int jj = 0; jj < 4; ++jj) {
        int rA = 8 * ks2 + jj, rB = rA + 4;
        short a16 = bf16_rn(S1[rA] * inv);
        short b16 = bf16_rn(S1[rB] * inv);
        int pk = (int)(unsigned short)a16 | (((int)b16) << 16);
        int xp = __shfl_xor(pk, 32, 64);
        tmp8[jj] = h == 0 ? a16 : (short)(xp >> 16);
        tmp8[4 + jj] = h == 0 ? (short)(xp & 0xffff) : b16;
      }
      *(short8*)&pbuf[kt1 * 2 + ks2][lane * 8] = *(short8*)tmp8;
    }
  }
  __syncthreads();
  const short* vbase = vpb + (size_t)bh * 128 * 256 * 8;
#pragma unroll
  for (int j = 0; j < 2; ++j) {
    int nt = wv * 2 + j;
    f32x16 acc;
#pragma unroll
    for (int r = 0; r < 16; ++r) acc[r] = 0.f;
    for (int kt = 0; kt < kt_n; ++kt) {
#pragma unroll
      for (int ks2 = 0; ks2 < 2; ++ks2) {
        short8 pfr = *(const short8*)&pbuf[kt * 2 + ks2][lane * 8];
        int sb = ks_lo + kt * 32 + ks2 * 16 + h * 8;
        short8 vf = *(const short8*)(vbase +
                                     ((size_t)(sb >> 3) * 256 + nt * 32 + l31) * 8);
        acc = __builtin_amdgcn_mfma_f32_32x32x16_bf16(pfr, vf, acc, 0, 0, 0);
      }
    }
    short* crow = ctxb + ((size_t)(b * 8 + nt) * T_DIM) * 256 + hh * 32 + l31;
#pragma unroll
    for (int r = 0; r < 16; ++r) {
      int t = qt0 + (r & 3) + 8 * (r >> 2) + 4 * h;
      if (t < T_DIM) crow[(size_t)t * 256] = bf16_rn(acc[r]);
    }
  }
}

// ---------------- proj: MFMA GEMM M=256 K=256 Ntile=32, 8 waves ------------
// grid 1024: id = tb*32 + bf  ->  id % 8 == bf % 8 (per-XCD ctx locality)
// w in fragment-order: addr = mblk*8192 + kk*512 + h*256 + l31*8
__global__ __launch_bounds__(512) void proj_mfma(
    const short* __restrict__ ctxb, const short* __restrict__ wb,
    const float* __restrict__ bias, const float* __restrict__ a_p,
    const float* __restrict__ gam, const float* __restrict__ bet,
    float* __restrict__ out) {
  __shared__ short Bs[32][264];
  __shared__ float lnS[8][32], lnQ[8][32];
  __shared__ float mu_s[32], ri_s[32];
  __shared__ float pb[256], pg[256], pe[256];
  int tid = threadIdx.x;
  int blk = blockIdx.x;
  int bf = blk & 31, tb = blk >> 5;
  int b = bf >> 3, f = bf & 7;
  int t0 = tb * 32;
  if (tid < 256) {
    pb[tid] = bias[tid];
    pg[tid] = gam[tid];
    pe[tid] = bet[tid];
  }
  {
    int row = tid >> 4, seg = (tid & 15) * 16;
    int t = t0 + row;
    if (t < T_DIM) {
      const short8* src =
          (const short8*)(ctxb + ((size_t)bf * T_DIM + t) * 256 + seg);
      *(short8*)&Bs[row][seg] = src[0];
      *(short8*)&Bs[row][seg + 8] = src[1];
    } else {
      short8 z = {0, 0, 0, 0, 0, 0, 0, 0};
      *(short8*)&Bs[row][seg] = z;
      *(short8*)&Bs[row][seg + 8] = z;
    }
  }
  __syncthreads();
  int lane = tid & 63, wv = tid >> 6;  // wv 0..7
  int h = lane >> 5, l31 = lane & 31;
  int m0 = wv * 32;
  f32x16 acc;
#pragma unroll
  for (int r = 0; r < 16; ++r) acc[r] = 0.f;
  const short* wfb = wb + (size_t)wv * 8192 + h * 256 + l31 * 8;
#pragma unroll
  for (int kk = 0; kk < 16; ++kk) {
    short8 bfr = *(const short8*)&Bs[l31][kk * 16 + h * 8];
    short8 af = *(const short8*)(wfb + kk * 512);
    acc = __builtin_amdgcn_mfma_f32_32x32x16_bf16(af, bfr, acc, 0, 0, 0);
  }
  float aslope = a_p[0];
  float s = 0.f, q = 0.f;
#pragma unroll
  for (int r = 0; r < 16; ++r) {
    int row = (r & 3) + 8 * (r >> 2) + 4 * h;
    int o = m0 + row;
    float v = acc[r] + pb[o];
    v = v >= 0.f ? v : aslope * v;
    acc[r] = v;
    s += v;
    q += v * v;
  }
  s += __shfl_xor(s, 32, 64);
  q += __shfl_xor(q, 32, 64);
  if (h == 0) {
    lnS[wv][l31] = s;
    lnQ[wv][l31] = q;
  }
  __syncthreads();
  if (tid < 32) {
    float ss = 0.f, qq = 0.f;
#pragma unroll
    for (int w = 0; w < 8; ++w) {
      ss += lnS[w][tid];
      qq += lnQ[w][tid];
    }
    float mu = ss * (1.f / 256.f);
    float var = qq * (1.f / 256.f) - mu * mu;
    mu_s[tid] = mu;
    ri_s[tid] = rsqrtf(var + 1e-5f);
  }
  __syncthreads();
  float mu = mu_s[l31], ri = ri_s[l31];
  int t = t0 + l31;
  if (t < T_DIM) {
#pragma unroll
    for (int r = 0; r < 16; ++r) {
      int row = (r & 3) + 8 * (r >> 2) + 4 * h;
      int o = m0 + row;
      float v = (acc[r] - mu) * ri * pg[o] + pe[o];
      out[((size_t)(b * 2048 + o * 8 + f)) * T_DIM + t] = v;
    }
  }
}

extern "C" void kernel_launch(void* const* d_in, const int* in_sizes, int n_in,
                              void* d_out, int out_size, void* d_ws,
                              size_t ws_size, hipStream_t stream) {
  const float* x = (const float*)d_in[0];
  const float* w_qkv = (const float*)d_in[1];
  const float* b_qkv = (const float*)d_in[2];
  const float* a_qkv = (const float*)d_in[3];
  const float* g_qkv = (const float*)d_in[4];
  const float* be_qkv = (const float*)d_in[5];
  const float* w_proj = (const float*)d_in[6];
  const float* b_proj = (const float*)d_in[7];
  const float* a_proj = (const float*)d_in[8];
  const float* g_proj = (const float*)d_in[9];
  const float* be_proj = (const float*)d_in[10];
  float* out = (float*)d_out;

  short* wqs = (short*)d_ws;            // 512*256 (fragment-order)
  short* wps = wqs + 131072;            // 256*256 (fragment-order)
  short* xbt = wps + 65536;             // 32000*256
  short* qkb = xbt + (size_t)8192000;   // 32*32*1024*8
  short* vpb = qkb + (size_t)8388608;   // 32*128*256*8
  short* ctxb = vpb + (size_t)8388608;  // 32000*256

  prep_w<<<768, 256, 0, stream>>>(w_qkv, w_proj, wqs, wps);
  xpose_x<<<dim3(4, 16, 32), 256, 0, stream>>>(x, xbt);
  qkv_mfma<<<1000, 512, 0, stream>>>(xbt, wqs, b_qkv, a_qkv, g_qkv, be_qkv,
                                     qkb, vpb);
  attn_mfma<<<dim3(32, 32), 256, 0, stream>>>(qkb, vpb, ctxb);
  proj_mfma<<<1024, 512, 0, stream>>>(ctxb, wps, b_proj, a_proj, g_proj,
                                      be_proj, out);
}